// Round 9
// baseline (611.572 us; speedup 1.0000x reference)
//
#include <hip/hip_runtime.h>

// RecurrentMambaCell: B=8192, D=2048, K=4, all fp32.
//   window   = concat(conv_state, x_t)            (B,D,4)
//   ncs      = window[:,:,1:]                     (B,D,3)
//   conv_out = sum_k window*W_conv[d,k] + b_conv  (B,D)
//   nss      = A*ssm + Bp*conv_out                (B,D)
//   y        = C*nss + D_skip*x                   (B,D)
// Pure streaming op: 320 MiB read + 336 MB write => HBM-bound, ~106us floor.
// R7 baseline: headline dur_us=581 (incl. ~320-330us harness reset; kernel
// itself <206us). R8 failed to compile: __builtin_nontemporal_* rejects
// HIP_vector_type. R9 = R8 with clang ext_vector_type instead of float4.

constexpr int kB = 8192;
constexpr int kD = 2048;
constexpr long long kN = (long long)kB * kD;   // 16,777,216 elements

typedef float f32x4 __attribute__((ext_vector_type(4)));  // clang vector: nt-builtin-compatible

__device__ __forceinline__ f32x4 ntload4(const float* p) {
    return __builtin_nontemporal_load((const f32x4*)p);
}
__device__ __forceinline__ void ntstore4(float* p, f32x4 v) {
    __builtin_nontemporal_store(v, (f32x4*)p);
}
__device__ __forceinline__ f32x4 cload4(const float* p) {   // cached path (params)
    return *(const f32x4*)p;
}

__global__ __launch_bounds__(256) void mamba_cell_kernel(
    const float* __restrict__ x_t,        // (B,D)
    const float* __restrict__ conv_state, // (B,D,3)
    const float* __restrict__ ssm_state,  // (B,D)
    const float* __restrict__ W_conv,     // (D,4)
    const float* __restrict__ b_conv,     // (D,)
    const float* __restrict__ A,          // (D,)
    const float* __restrict__ Bp,         // (D,)
    const float* __restrict__ C,          // (D,)
    const float* __restrict__ D_skip,     // (D,)
    float* __restrict__ y_out,            // (B,D)
    float* __restrict__ ncs_out,          // (B,D,3)
    float* __restrict__ nss_out)          // (B,D)
{
    const long long ngroups = kN / 4;     // 4 elements (one 16B group) per thread-iter
    const long long tid0    = (long long)blockIdx.x * blockDim.x + threadIdx.x;
    const long long gstride = (long long)gridDim.x * blockDim.x;

    // d0 is loop-invariant: gstride*4 elements = 2^21, a multiple of D=2048.
    // (Launch fixes grid=2048, block=256 — do not change without rechecking.)
    const int d0 = (int)((tid0 * 4) & (kD - 1));

    // --- loop-invariant per-d parameters (cached path: reused grid-wide) ---
    const f32x4 w0 = cload4(W_conv + (long long)(d0 + 0) * 4);
    const f32x4 w1 = cload4(W_conv + (long long)(d0 + 1) * 4);
    const f32x4 w2 = cload4(W_conv + (long long)(d0 + 2) * 4);
    const f32x4 w3 = cload4(W_conv + (long long)(d0 + 3) * 4);
    const f32x4 bc = cload4(b_conv + d0);
    const f32x4 a  = cload4(A + d0);
    const f32x4 bp = cload4(Bp + d0);
    const f32x4 cc = cload4(C + d0);
    const f32x4 ds = cload4(D_skip + d0);

    for (long long g = tid0; g < ngroups; g += gstride) {
        const long long i = g * 4;            // element index of group start

        // --- streamed loads (touch-once -> nontemporal) ---
        const f32x4 x  = ntload4(x_t + i);
        const f32x4 s  = ntload4(ssm_state + i);
        const f32x4 c0 = ntload4(conv_state + 3 * i);      // e0k0 e0k1 e0k2 e1k0
        const f32x4 c1 = ntload4(conv_state + 3 * i + 4);  // e1k1 e1k2 e2k0 e2k1
        const f32x4 c2 = ntload4(conv_state + 3 * i + 8);  // e2k2 e3k0 e3k1 e3k2

        // --- conv_out = window . W_conv + b_conv (K=4, last tap is x) ---
        const float co0 = c0[0] * w0[0] + c0[1] * w0[1] + c0[2] * w0[2] + x[0] * w0[3] + bc[0];
        const float co1 = c0[3] * w1[0] + c1[0] * w1[1] + c1[1] * w1[2] + x[1] * w1[3] + bc[1];
        const float co2 = c1[2] * w2[0] + c1[3] * w2[1] + c2[0] * w2[2] + x[2] * w2[3] + bc[2];
        const float co3 = c2[1] * w3[0] + c2[2] * w3[1] + c2[3] * w3[2] + x[3] * w3[3] + bc[3];

        // --- SSM update + output ---
        f32x4 ns;
        ns[0] = a[0] * s[0] + bp[0] * co0;
        ns[1] = a[1] * s[1] + bp[1] * co1;
        ns[2] = a[2] * s[2] + bp[2] * co2;
        ns[3] = a[3] * s[3] + bp[3] * co3;

        f32x4 y;
        y[0] = cc[0] * ns[0] + ds[0] * x[0];
        y[1] = cc[1] * ns[1] + ds[1] * x[1];
        y[2] = cc[2] * ns[2] + ds[2] * x[2];
        y[3] = cc[3] * ns[3] + ds[3] * x[3];

        // --- new conv state: per element (k1, k2, x) ---
        f32x4 o0, o1, o2;
        o0[0] = c0[1]; o0[1] = c0[2]; o0[2] = x[0]; o0[3] = c1[0];   // e0k1 e0k2 x0 | e1k1
        o1[0] = c1[1]; o1[1] = x[1];  o1[2] = c1[3]; o1[3] = c2[0];  // e1k2 x1 | e2k1 e2k2
        o2[0] = x[2];  o2[1] = c2[2]; o2[2] = c2[3]; o2[3] = x[3];   // x2 | e3k1 e3k2 x3

        // --- streamed stores (written-once -> nontemporal) ---
        ntstore4(y_out + i,           y);
        ntstore4(nss_out + i,         ns);
        ntstore4(ncs_out + 3 * i,     o0);
        ntstore4(ncs_out + 3 * i + 4, o1);
        ntstore4(ncs_out + 3 * i + 8, o2);
    }
}

extern "C" void kernel_launch(void* const* d_in, const int* in_sizes, int n_in,
                              void* d_out, int out_size, void* d_ws, size_t ws_size,
                              hipStream_t stream) {
    const float* x_t        = (const float*)d_in[0];
    const float* conv_state = (const float*)d_in[1];
    const float* ssm_state  = (const float*)d_in[2];
    const float* W_conv     = (const float*)d_in[3];
    const float* b_conv     = (const float*)d_in[4];
    const float* A          = (const float*)d_in[5];
    const float* Bp         = (const float*)d_in[6];
    const float* C          = (const float*)d_in[7];
    const float* D_skip     = (const float*)d_in[8];

    // d_out layout: y_t (N) | new_conv_state (3N) | new_ssm_state (N)
    float* y_out   = (float*)d_out;
    float* ncs_out = y_out + kN;
    float* nss_out = y_out + 4 * kN;

    // grid=2048, block=256: required for the d0 loop-invariance above
    // (gridDim*blockDim*4 must be a multiple of D).
    const int block = 256;
    const int grid  = 2048;
    mamba_cell_kernel<<<grid, block, 0, stream>>>(
        x_t, conv_state, ssm_state, W_conv, b_conv, A, Bp, C, D_skip,
        y_out, ncs_out, nss_out);
}

// Round 10
// 571.537 us; speedup vs baseline: 1.0700x; 1.0700x over previous
//
#include <hip/hip_runtime.h>

// RecurrentMambaCell: B=8192, D=2048, K=4, all fp32.
// R7 baseline: 581.4us headline (incl. ~370us harness reset; kernel <207us).
// R9 (hoist + nt-everything): 611.6us (+30). Theory: nt on the 48B-stride
// conv_state/ncs streams breaks cross-instruction L2 line reuse (3x 16B
// instrs share 128B lines across lanes) -> HBM refetch + broken write-combine.
// R10: hoist kept; nt ONLY on dense streams (x, ssm, y, nss); conv_state/ncs
// back to cached path. Predict: <=581.

constexpr int kB = 8192;
constexpr int kD = 2048;
constexpr long long kN = (long long)kB * kD;   // 16,777,216 elements

typedef float f32x4 __attribute__((ext_vector_type(4)));  // clang vector: nt-builtin-compatible

__device__ __forceinline__ f32x4 ntload4(const float* p) {
    return __builtin_nontemporal_load((const f32x4*)p);
}
__device__ __forceinline__ void ntstore4(float* p, f32x4 v) {
    __builtin_nontemporal_store(v, (f32x4*)p);
}
__device__ __forceinline__ f32x4 cload4(const float* p) {   // cached path
    return *(const f32x4*)p;
}

__global__ __launch_bounds__(256) void mamba_cell_kernel(
    const float* __restrict__ x_t,        // (B,D)
    const float* __restrict__ conv_state, // (B,D,3)
    const float* __restrict__ ssm_state,  // (B,D)
    const float* __restrict__ W_conv,     // (D,4)
    const float* __restrict__ b_conv,     // (D,)
    const float* __restrict__ A,          // (D,)
    const float* __restrict__ Bp,         // (D,)
    const float* __restrict__ C,          // (D,)
    const float* __restrict__ D_skip,     // (D,)
    float* __restrict__ y_out,            // (B,D)
    float* __restrict__ ncs_out,          // (B,D,3)
    float* __restrict__ nss_out)          // (B,D)
{
    const long long ngroups = kN / 4;     // 4 elements (one 16B group) per thread-iter
    const long long tid0    = (long long)blockIdx.x * blockDim.x + threadIdx.x;
    const long long gstride = (long long)gridDim.x * blockDim.x;

    // d0 is loop-invariant: gstride*4 elements = 2^21, a multiple of D=2048.
    // (Launch fixes grid=2048, block=256 — do not change without rechecking.)
    const int d0 = (int)((tid0 * 4) & (kD - 1));

    // --- loop-invariant per-d parameters (cached; reused grid-wide) ---
    const f32x4 w0 = cload4(W_conv + (long long)(d0 + 0) * 4);
    const f32x4 w1 = cload4(W_conv + (long long)(d0 + 1) * 4);
    const f32x4 w2 = cload4(W_conv + (long long)(d0 + 2) * 4);
    const f32x4 w3 = cload4(W_conv + (long long)(d0 + 3) * 4);
    const f32x4 bc = cload4(b_conv + d0);
    const f32x4 a  = cload4(A + d0);
    const f32x4 bp = cload4(Bp + d0);
    const f32x4 cc = cload4(C + d0);
    const f32x4 ds = cload4(D_skip + d0);

    for (long long g = tid0; g < ngroups; g += gstride) {
        const long long i = g * 4;            // element index of group start

        // --- dense streams: one instr fully covers its lines -> nt safe ---
        const f32x4 x  = ntload4(x_t + i);
        const f32x4 s  = ntload4(ssm_state + i);
        // --- interleaved 48B-stride streams: keep cached (L2 line reuse
        //     across the 3 instructions; nt here caused the R9 regression) ---
        const f32x4 c0 = cload4(conv_state + 3 * i);      // e0k0 e0k1 e0k2 e1k0
        const f32x4 c1 = cload4(conv_state + 3 * i + 4);  // e1k1 e1k2 e2k0 e2k1
        const f32x4 c2 = cload4(conv_state + 3 * i + 8);  // e2k2 e3k0 e3k1 e3k2

        // --- conv_out = window . W_conv + b_conv (K=4, last tap is x) ---
        const float co0 = c0[0] * w0[0] + c0[1] * w0[1] + c0[2] * w0[2] + x[0] * w0[3] + bc[0];
        const float co1 = c0[3] * w1[0] + c1[0] * w1[1] + c1[1] * w1[2] + x[1] * w1[3] + bc[1];
        const float co2 = c1[2] * w2[0] + c1[3] * w2[1] + c2[0] * w2[2] + x[2] * w2[3] + bc[2];
        const float co3 = c2[1] * w3[0] + c2[2] * w3[1] + c2[3] * w3[2] + x[3] * w3[3] + bc[3];

        // --- SSM update + output ---
        f32x4 ns;
        ns[0] = a[0] * s[0] + bp[0] * co0;
        ns[1] = a[1] * s[1] + bp[1] * co1;
        ns[2] = a[2] * s[2] + bp[2] * co2;
        ns[3] = a[3] * s[3] + bp[3] * co3;

        f32x4 y;
        y[0] = cc[0] * ns[0] + ds[0] * x[0];
        y[1] = cc[1] * ns[1] + ds[1] * x[1];
        y[2] = cc[2] * ns[2] + ds[2] * x[2];
        y[3] = cc[3] * ns[3] + ds[3] * x[3];

        // --- new conv state: per element (k1, k2, x) ---
        f32x4 o0, o1, o2;
        o0[0] = c0[1]; o0[1] = c0[2]; o0[2] = x[0]; o0[3] = c1[0];   // e0k1 e0k2 x0 | e1k1
        o1[0] = c1[1]; o1[1] = x[1];  o1[2] = c1[3]; o1[3] = c2[0];  // e1k2 x1 | e2k1 e2k2
        o2[0] = x[2];  o2[1] = c2[2]; o2[2] = c2[3]; o2[3] = x[3];   // x2 | e3k1 e3k2 x3

        // --- dense output streams -> nt; interleaved ncs -> cached ---
        ntstore4(y_out + i,   y);
        ntstore4(nss_out + i, ns);
        *(f32x4*)(ncs_out + 3 * i)     = o0;
        *(f32x4*)(ncs_out + 3 * i + 4) = o1;
        *(f32x4*)(ncs_out + 3 * i + 8) = o2;
    }
}

extern "C" void kernel_launch(void* const* d_in, const int* in_sizes, int n_in,
                              void* d_out, int out_size, void* d_ws, size_t ws_size,
                              hipStream_t stream) {
    const float* x_t        = (const float*)d_in[0];
    const float* conv_state = (const float*)d_in[1];
    const float* ssm_state  = (const float*)d_in[2];
    const float* W_conv     = (const float*)d_in[3];
    const float* b_conv     = (const float*)d_in[4];
    const float* A          = (const float*)d_in[5];
    const float* Bp         = (const float*)d_in[6];
    const float* C          = (const float*)d_in[7];
    const float* D_skip     = (const float*)d_in[8];

    // d_out layout: y_t (N) | new_conv_state (3N) | new_ssm_state (N)
    float* y_out   = (float*)d_out;
    float* ncs_out = y_out + kN;
    float* nss_out = y_out + 4 * kN;

    // grid=2048, block=256: required for the d0 loop-invariance above
    // (gridDim*blockDim*4 must be a multiple of D).
    const int block = 256;
    const int grid  = 2048;
    mamba_cell_kernel<<<grid, block, 0, stream>>>(
        x_t, conv_state, ssm_state, W_conv, b_conv, A, Bp, C, D_skip,
        y_out, ncs_out, nss_out);
}